// Round 1
// baseline (571.998 us; speedup 1.0000x reference)
//
#include <hip/hip_runtime.h>

#define B_   2
#define S_   2048
#define H_   2048
#define NH_  16
#define HS_  128
#define NORM_ 0.08838834764831845f          // 128^-0.5
#define L2B16 0.8304820237218407f           // log2(10000)/16

typedef unsigned short bf16_t;
typedef __bf16 bf16x8 __attribute__((ext_vector_type(8)));
typedef float  f32x4  __attribute__((ext_vector_type(4)));

__device__ __forceinline__ float b2f(bf16_t u) {
    return __uint_as_float(((unsigned int)u) << 16);
}
__device__ __forceinline__ bf16_t f2b(float f) {
    unsigned int x = __float_as_uint(f);
    x += 0x7fffu + ((x >> 16) & 1u);        // round-to-nearest-even
    return (bf16_t)(x >> 16);
}

__device__ __forceinline__ void async16(bf16_t* lds, const bf16_t* g) {
    __builtin_amdgcn_global_load_lds(
        (const __attribute__((address_space(1))) void*)g,
        (__attribute__((address_space(3))) void*)lds, 16, 0, 0);
}

__device__ __forceinline__ f32x4 mfma16(bf16x8 a, bf16x8 b, f32x4 c) {
    return __builtin_amdgcn_mfma_f32_16x16x32_bf16(a, b, c, 0, 0, 0);
}

// ---------------- f32 -> bf16 convert (8 elems/thread) ----------------
__global__ __launch_bounds__(256) void cvt_bf16(const float* __restrict__ in,
                                                bf16_t* __restrict__ out) {
    const size_t i = (size_t)blockIdx.x * 256 + threadIdx.x;
    const float4* p = (const float4*)in + i * 2;
    float4 a = p[0], b = p[1];
    bf16_t o[8] = { f2b(a.x), f2b(a.y), f2b(a.z), f2b(a.w),
                    f2b(b.x), f2b(b.y), f2b(b.z), f2b(b.w) };
    *((bf16x8*)out + i) = *(const bf16x8*)o;
}

// ---------------- W (KxN f32) -> W^T (NxK bf16), 32x32 tiles ----------------
__global__ __launch_bounds__(256) void transpose_cvt(const float* __restrict__ W,
                                                     bf16_t* __restrict__ WT,
                                                     int K, int N) {
    __shared__ float tile[32][33];
    const int tx = threadIdx.x & 31, ty = threadIdx.x >> 5;
    const int n0 = blockIdx.x * 32, k0 = blockIdx.y * 32;
#pragma unroll
    for (int i = 0; i < 4; i++)
        tile[ty + i * 8][tx] = W[(size_t)(k0 + ty + i * 8) * N + n0 + tx];
    __syncthreads();
#pragma unroll
    for (int i = 0; i < 4; i++)
        WT[(size_t)(n0 + ty + i * 8) * K + k0 + tx] = f2b(tile[tx][ty + i * 8]);
}

// ---------------- GEMM: C = A(MxK) @ BT(NxK)^T + bias ----------------
// 128x128 tile, BK=32, 4 waves (2x2), 16x16x32 bf16 MFMA, global_load_lds.
template <int BF16OUT>
__global__ __launch_bounds__(256) void gemm_bias(const bf16_t* __restrict__ A,
                                                 const bf16_t* __restrict__ BT,
                                                 const float* __restrict__ bias,
                                                 void* __restrict__ Cv,
                                                 int M, int N, int K) {
    __shared__ __align__(16) bf16_t As[128 * 32];
    __shared__ __align__(16) bf16_t Bs[128 * 32];
    const int tid = threadIdx.x;
    const int wid = tid >> 6, lane = tid & 63;
    const int lr = lane & 15, ls = lane >> 4;
    const int wr = wid >> 1, wc = wid & 1;
    const size_t m0 = (size_t)blockIdx.y * 128, n0 = (size_t)blockIdx.x * 128;

    f32x4 acc[4][4];
#pragma unroll
    for (int m = 0; m < 4; m++)
#pragma unroll
        for (int n = 0; n < 4; n++) acc[m][n] = (f32x4){0.f, 0.f, 0.f, 0.f};

    const int srow = lane >> 2, sk = (lane & 3) * 8;

    for (int k0 = 0; k0 < K; k0 += 32) {
        __syncthreads();
#pragma unroll
        for (int j = 0; j < 2; j++) {
            const int rr = (wid * 2 + j) * 16 + srow;
            async16(As + (wid * 2 + j) * 512, A + (m0 + rr) * K + k0 + sk);
            async16(Bs + (wid * 2 + j) * 512, BT + (n0 + rr) * K + k0 + sk);
        }
        __syncthreads();
        bf16x8 af[4], bfr[4];
#pragma unroll
        for (int m = 0; m < 4; m++)
            af[m] = *(const bf16x8*)&As[(wr * 64 + m * 16 + lr) * 32 + ls * 8];
#pragma unroll
        for (int n = 0; n < 4; n++)
            bfr[n] = *(const bf16x8*)&Bs[(wc * 64 + n * 16 + lr) * 32 + ls * 8];
#pragma unroll
        for (int m = 0; m < 4; m++)
#pragma unroll
            for (int n = 0; n < 4; n++)
                acc[m][n] = mfma16(af[m], bfr[n], acc[m][n]);
    }

    float bv[4];
#pragma unroll
    for (int n = 0; n < 4; n++) bv[n] = bias[n0 + wc * 64 + n * 16 + lr];
#pragma unroll
    for (int m = 0; m < 4; m++)
#pragma unroll
        for (int n = 0; n < 4; n++)
#pragma unroll
            for (int j = 0; j < 4; j++) {
                const size_t row = m0 + wr * 64 + m * 16 + ls * 4 + j;
                const size_t col = n0 + wc * 64 + n * 16 + lr;
                const float v = acc[m][n][j] + bv[n];
                if (BF16OUT) ((bf16_t*)Cv)[row * N + col] = f2b(v);
                else         ((float*)Cv)[row * N + col] = v;
            }
}

// ---------------- RoPE + scatter to Q, K, V^T ----------------
// thread = (b,s,nh,which,d8): 8 contiguous dims of one head-row
__global__ __launch_bounds__(256) void rope_scatter(const bf16_t* __restrict__ qkv,
                                                    const int* __restrict__ pos_ids,
                                                    bf16_t* __restrict__ Qo,
                                                    bf16_t* __restrict__ Ko,
                                                    bf16_t* __restrict__ Vt) {
    const size_t gid = (size_t)blockIdx.x * 256 + threadIdx.x;
    const int d8 = (int)(gid & 15);
    const size_t t1 = gid >> 4;
    const int which = (int)(t1 % 3);
    const size_t t2 = t1 / 3;
    const int nh = (int)(t2 & 15);
    const size_t bs = t2 >> 4;                  // b*S + s
    const int s = (int)(bs & (S_ - 1));
    const int b = (int)(bs >> 11);

    const bf16_t* src = qkv + bs * (3 * H_) + nh * 384 + which * 128 + d8 * 8;
    bf16x8 xv = *(const bf16x8*)src;
    const bf16_t* xu = (const bf16_t*)&xv;

    if (which == 2) {                           // V: transpose to (bh, HS, S)
        bf16_t* vb = Vt + ((size_t)(b * NH_ + nh) * HS_ + d8 * 8) * S_ + s;
#pragma unroll
        for (int i = 0; i < 8; i++) vb[(size_t)i * S_] = xu[i];
        return;
    }
    float xf[8];
#pragma unroll
    for (int i = 0; i < 8; i++) xf[i] = b2f(xu[i]);
    const int d0 = d8 * 8;
    if (d0 < 32) {                              // rotary on first 32 dims
        const float pos = (float)pos_ids[bs];
        bf16x8 yv = *(const bf16x8*)(src + ((d0 < 16) ? 16 : -16));
        const bf16_t* yu = (const bf16_t*)&yv;
#pragma unroll
        for (int i = 0; i < 8; i++) {
            const int d = d0 + i;
            const float th = pos * exp2f(-(float)(d & 15) * L2B16);
            const float c = cosf(th), sn = sinf(th);
            const float rot = (d < 16) ? -b2f(yu[i]) : b2f(yu[i]);
            xf[i] = xf[i] * c + rot * sn;
        }
    }
    bf16_t ou[8];
#pragma unroll
    for (int i = 0; i < 8; i++) ou[i] = f2b(xf[i]);
    bf16_t* dst = ((which == 0) ? Qo : Ko) + ((size_t)(b * NH_ + nh) * S_ + s) * HS_ + d0;
    *(bf16x8*)dst = *(const bf16x8*)ou;
}

// ---------------- causal flash attention ----------------
// block: one (b,h), 64 q-rows (4 waves x 16). KB=32 kv-steps, K/V^T in LDS.
__global__ __launch_bounds__(256) void attn_fwd(const bf16_t* __restrict__ Q,
                                                const bf16_t* __restrict__ Kv,
                                                const bf16_t* __restrict__ Vt,
                                                const float* __restrict__ amask,
                                                bf16_t* __restrict__ ctx) {
    __shared__ __align__(16) bf16_t Ks[32 * 128];
    __shared__ __align__(16) bf16_t Vs[128 * 32];
    __shared__ __align__(16) bf16_t Ps[4][16 * 32];
    const int bh = blockIdx.y;
    const int b = bh >> 4, h = bh & 15;
    const int qt = (int)gridDim.x - 1 - blockIdx.x;   // heavy tiles first
    const int q0 = qt * 64;
    const int tid = threadIdx.x, wid = tid >> 6, lane = tid & 63;
    const int lr = lane & 15, ls = lane >> 4;

    bf16x8 qf[4];
    const bf16_t* qp = Q + ((size_t)bh * S_ + q0 + wid * 16 + lr) * HS_;
#pragma unroll
    for (int dk = 0; dk < 4; dk++) qf[dk] = *(const bf16x8*)(qp + dk * 32 + ls * 8);

    float mrun[4], lrun[4];
    f32x4 oacc[8];
#pragma unroll
    for (int j = 0; j < 4; j++) { mrun[j] = -3.0e38f; lrun[j] = 0.f; }
#pragma unroll
    for (int dt = 0; dt < 8; dt++) oacc[dt] = (f32x4){0.f, 0.f, 0.f, 0.f};

    const float* am = amask + (size_t)b * S_;
    const int qrb = q0 + wid * 16 + ls * 4;

    for (int kv0 = 0; kv0 < q0 + 64; kv0 += 32) {
        __syncthreads();
#pragma unroll
        for (int j = 0; j < 2; j++) {
            const int rK = (wid * 2 + j) * 4 + ls;
            async16(Ks + (wid * 2 + j) * 512,
                    Kv + ((size_t)bh * S_ + kv0 + rK) * HS_ + lr * 8);
            const int rV = (wid * 2 + j) * 16 + (lane >> 2);
            async16(Vs + (wid * 2 + j) * 512,
                    Vt + ((size_t)bh * HS_ + rV) * S_ + kv0 + (lane & 3) * 8);
        }
        __syncthreads();

        f32x4 sacc[2];
        sacc[0] = (f32x4){0.f, 0.f, 0.f, 0.f};
        sacc[1] = (f32x4){0.f, 0.f, 0.f, 0.f};
#pragma unroll
        for (int t = 0; t < 2; t++)
#pragma unroll
            for (int dk = 0; dk < 4; dk++) {
                bf16x8 kf = *(const bf16x8*)&Ks[(t * 16 + lr) * 128 + dk * 32 + ls * 8];
                sacc[t] = mfma16(qf[dk], kf, sacc[t]);
            }

        float sv[2][4], rmax[4], scj[4], psum[4];
#pragma unroll
        for (int j = 0; j < 4; j++) {
#pragma unroll
            for (int t = 0; t < 2; t++) {
                const int kvp = kv0 + t * 16 + lr;
                float v = sacc[t][j] * NORM_ + am[kvp];
                if (kvp > qrb + j) v = -3.0e38f;
                sv[t][j] = v;
            }
            rmax[j] = fmaxf(sv[0][j], sv[1][j]);
        }
#pragma unroll
        for (int off = 1; off < 16; off <<= 1)
#pragma unroll
            for (int j = 0; j < 4; j++)
                rmax[j] = fmaxf(rmax[j], __shfl_xor(rmax[j], off));
#pragma unroll
        for (int j = 0; j < 4; j++) {
            const float mnew = fmaxf(mrun[j], rmax[j]);
            scj[j] = __expf(mrun[j] - mnew);
            mrun[j] = mnew;
            const float p0 = __expf(sv[0][j] - mnew);
            const float p1 = __expf(sv[1][j] - mnew);
            psum[j] = p0 + p1;
            Ps[wid][(ls * 4 + j) * 32 + lr]      = f2b(p0);
            Ps[wid][(ls * 4 + j) * 32 + 16 + lr] = f2b(p1);
        }
#pragma unroll
        for (int off = 1; off < 16; off <<= 1)
#pragma unroll
            for (int j = 0; j < 4; j++) psum[j] += __shfl_xor(psum[j], off);
#pragma unroll
        for (int j = 0; j < 4; j++) {
            lrun[j] = lrun[j] * scj[j] + psum[j];
#pragma unroll
            for (int dt = 0; dt < 8; dt++) oacc[dt][j] *= scj[j];
        }

        bf16x8 pf = *(const bf16x8*)&Ps[wid][lr * 32 + ls * 8];
#pragma unroll
        for (int dt = 0; dt < 8; dt++) {
            bf16x8 vf = *(const bf16x8*)&Vs[(dt * 16 + lr) * 32 + ls * 8];
            oacc[dt] = mfma16(pf, vf, oacc[dt]);
        }
    }

#pragma unroll
    for (int j = 0; j < 4; j++) {
        const float inv = 1.0f / lrun[j];
        bf16_t* dst = ctx + ((size_t)b * S_ + q0 + wid * 16 + ls * 4 + j) * H_ + h * HS_;
#pragma unroll
        for (int dt = 0; dt < 8; dt++) dst[dt * 16 + lr] = f2b(oacc[dt][j] * inv);
    }
}

extern "C" void kernel_launch(void* const* d_in, const int* in_sizes, int n_in,
                              void* d_out, int out_size, void* d_ws, size_t ws_size,
                              hipStream_t stream) {
    const float* hs   = (const float*)d_in[0];
    const float* am   = (const float*)d_in[1];
    const int*   pos  = (const int*)d_in[2];
    const float* Wqkv = (const float*)d_in[3];
    const float* bqkv = (const float*)d_in[4];
    const float* Wd   = (const float*)d_in[5];
    const float* bd   = (const float*)d_in[6];
    float* out = (float*)d_out;
    char*  ws  = (char*)d_ws;

    const size_t MB = 1024 * 1024;
    bf16_t* X    = (bf16_t*)(ws);              // 16 MB (reused as ctx)
    bf16_t* WqT  = (bf16_t*)(ws + 16 * MB);    // 24 MB
    bf16_t* WdT  = (bf16_t*)(ws + 40 * MB);    // 8 MB
    bf16_t* QKVb = (bf16_t*)(ws + 48 * MB);    // 48 MB
    bf16_t* Qb   = (bf16_t*)(ws + 96 * MB);    // 16 MB
    bf16_t* Kb   = (bf16_t*)(ws + 112 * MB);   // 16 MB
    bf16_t* Vtb  = (bf16_t*)(ws + 128 * MB);   // 16 MB
    bf16_t* ctx  = X;

    cvt_bf16<<<4096, 256, 0, stream>>>(hs, X);                       // 2*2048*2048/8
    transpose_cvt<<<dim3(6144 / 32, 2048 / 32), 256, 0, stream>>>(Wqkv, WqT, 2048, 6144);
    transpose_cvt<<<dim3(2048 / 32, 2048 / 32), 256, 0, stream>>>(Wd, WdT, 2048, 2048);
    gemm_bias<1><<<dim3(6144 / 128, 4096 / 128), 256, 0, stream>>>(X, WqT, bqkv, QKVb,
                                                                   4096, 6144, 2048);
    rope_scatter<<<12288, 256, 0, stream>>>(QKVb, pos, Qb, Kb, Vtb); // 2*2048*16*48/256
    attn_fwd<<<dim3(32, 32), 256, 0, stream>>>(Qb, Kb, Vtb, am, ctx);
    gemm_bias<0><<<dim3(2048 / 128, 4096 / 128), 256, 0, stream>>>(ctx, WdT, bd, out,
                                                                   4096, 2048, 2048);
}

// Round 2
// 371.929 us; speedup vs baseline: 1.5379x; 1.5379x over previous
//
#include <hip/hip_runtime.h>

#define B_   2
#define S_   2048
#define H_   2048
#define NH_  16
#define HS_  128
#define NORM_ 0.08838834764831845f          // 128^-0.5
#define L2B16 0.8304820237218407f           // log2(10000)/16

typedef unsigned short bf16_t;
typedef __bf16 bf16x8 __attribute__((ext_vector_type(8)));
typedef float  f32x4  __attribute__((ext_vector_type(4)));

__device__ __forceinline__ float b2f(bf16_t u) {
    return __uint_as_float(((unsigned int)u) << 16);
}
__device__ __forceinline__ bf16_t f2b(float f) {
    unsigned int x = __float_as_uint(f);
    x += 0x7fffu + ((x >> 16) & 1u);        // round-to-nearest-even
    return (bf16_t)(x >> 16);
}

__device__ __forceinline__ void async16(bf16_t* lds, const bf16_t* g) {
    __builtin_amdgcn_global_load_lds(
        (const __attribute__((address_space(1))) void*)g,
        (__attribute__((address_space(3))) void*)lds, 16, 0, 0);
}

__device__ __forceinline__ f32x4 mfma16(bf16x8 a, bf16x8 b, f32x4 c) {
    return __builtin_amdgcn_mfma_f32_16x16x32_bf16(a, b, c, 0, 0, 0);
}

// ---------------- f32 -> bf16 convert (8 elems/thread) ----------------
__global__ __launch_bounds__(256) void cvt_bf16(const float* __restrict__ in,
                                                bf16_t* __restrict__ out) {
    const size_t i = (size_t)blockIdx.x * 256 + threadIdx.x;
    const float4* p = (const float4*)in + i * 2;
    float4 a = p[0], b = p[1];
    bf16_t o[8] = { f2b(a.x), f2b(a.y), f2b(a.z), f2b(a.w),
                    f2b(b.x), f2b(b.y), f2b(b.z), f2b(b.w) };
    *((bf16x8*)out + i) = *(const bf16x8*)o;
}

// ---------------- W (KxN f32) -> W^T (NxK bf16), 32x32 tiles ----------------
__global__ __launch_bounds__(256) void transpose_cvt(const float* __restrict__ W,
                                                     bf16_t* __restrict__ WT,
                                                     int K, int N) {
    __shared__ float tile[32][33];
    const int tx = threadIdx.x & 31, ty = threadIdx.x >> 5;
    const int n0 = blockIdx.x * 32, k0 = blockIdx.y * 32;
#pragma unroll
    for (int i = 0; i < 4; i++)
        tile[ty + i * 8][tx] = W[(size_t)(k0 + ty + i * 8) * N + n0 + tx];
    __syncthreads();
#pragma unroll
    for (int i = 0; i < 4; i++)
        WT[(size_t)(n0 + ty + i * 8) * K + k0 + tx] = f2b(tile[tx][ty + i * 8]);
}

// ---------------- GEMM: C = A(MxK) @ BT(NxK)^T + bias ----------------
// 128x128 tile, BK=32, 4 waves (2x2), 16x16x32 bf16 MFMA, global_load_lds.
template <int BF16OUT>
__global__ __launch_bounds__(256) void gemm_bias(const bf16_t* __restrict__ A,
                                                 const bf16_t* __restrict__ BT,
                                                 const float* __restrict__ bias,
                                                 void* __restrict__ Cv,
                                                 int M, int N, int K) {
    __shared__ __align__(16) bf16_t As[128 * 32];
    __shared__ __align__(16) bf16_t Bs[128 * 32];
    const int tid = threadIdx.x;
    const int wid = tid >> 6, lane = tid & 63;
    const int lr = lane & 15, ls = lane >> 4;
    const int wr = wid >> 1, wc = wid & 1;
    const size_t m0 = (size_t)blockIdx.y * 128, n0 = (size_t)blockIdx.x * 128;

    f32x4 acc[4][4];
#pragma unroll
    for (int m = 0; m < 4; m++)
#pragma unroll
        for (int n = 0; n < 4; n++) acc[m][n] = (f32x4){0.f, 0.f, 0.f, 0.f};

    const int srow = lane >> 2, sk = (lane & 3) * 8;

    for (int k0 = 0; k0 < K; k0 += 32) {
        __syncthreads();
#pragma unroll
        for (int j = 0; j < 2; j++) {
            const int rr = (wid * 2 + j) * 16 + srow;
            async16(As + (wid * 2 + j) * 512, A + (m0 + rr) * K + k0 + sk);
            async16(Bs + (wid * 2 + j) * 512, BT + (n0 + rr) * K + k0 + sk);
        }
        __syncthreads();
        bf16x8 af[4], bfr[4];
#pragma unroll
        for (int m = 0; m < 4; m++)
            af[m] = *(const bf16x8*)&As[(wr * 64 + m * 16 + lr) * 32 + ls * 8];
#pragma unroll
        for (int n = 0; n < 4; n++)
            bfr[n] = *(const bf16x8*)&Bs[(wc * 64 + n * 16 + lr) * 32 + ls * 8];
#pragma unroll
        for (int m = 0; m < 4; m++)
#pragma unroll
            for (int n = 0; n < 4; n++)
                acc[m][n] = mfma16(af[m], bfr[n], acc[m][n]);
    }

    float bv[4];
#pragma unroll
    for (int n = 0; n < 4; n++) bv[n] = bias[n0 + wc * 64 + n * 16 + lr];
#pragma unroll
    for (int m = 0; m < 4; m++)
#pragma unroll
        for (int n = 0; n < 4; n++)
#pragma unroll
            for (int j = 0; j < 4; j++) {
                const size_t row = m0 + wr * 64 + m * 16 + ls * 4 + j;
                const size_t col = n0 + wc * 64 + n * 16 + lr;
                const float v = acc[m][n][j] + bv[n];
                if (BF16OUT) ((bf16_t*)Cv)[row * N + col] = f2b(v);
                else         ((float*)Cv)[row * N + col] = v;
            }
}

// ---------------- RoPE + scatter to Q, K, V^T ----------------
__global__ __launch_bounds__(256) void rope_scatter(const bf16_t* __restrict__ qkv,
                                                    const int* __restrict__ pos_ids,
                                                    bf16_t* __restrict__ Qo,
                                                    bf16_t* __restrict__ Ko,
                                                    bf16_t* __restrict__ Vt) {
    const size_t gid = (size_t)blockIdx.x * 256 + threadIdx.x;
    const int d8 = (int)(gid & 15);
    const size_t t1 = gid >> 4;
    const int which = (int)(t1 % 3);
    const size_t t2 = t1 / 3;
    const int nh = (int)(t2 & 15);
    const size_t bs = t2 >> 4;                  // b*S + s
    const int s = (int)(bs & (S_ - 1));
    const int b = (int)(bs >> 11);

    const bf16_t* src = qkv + bs * (3 * H_) + nh * 384 + which * 128 + d8 * 8;
    bf16x8 xv = *(const bf16x8*)src;
    const bf16_t* xu = (const bf16_t*)&xv;

    if (which == 2) {                           // V: transpose to (bh, HS, S)
        bf16_t* vb = Vt + ((size_t)(b * NH_ + nh) * HS_ + d8 * 8) * S_ + s;
#pragma unroll
        for (int i = 0; i < 8; i++) vb[(size_t)i * S_] = xu[i];
        return;
    }
    float xf[8];
#pragma unroll
    for (int i = 0; i < 8; i++) xf[i] = b2f(xu[i]);
    const int d0 = d8 * 8;
    if (d0 < 32) {                              // rotary on first 32 dims
        const float pos = (float)pos_ids[bs];
        bf16x8 yv = *(const bf16x8*)(src + ((d0 < 16) ? 16 : -16));
        const bf16_t* yu = (const bf16_t*)&yv;
#pragma unroll
        for (int i = 0; i < 8; i++) {
            const int d = d0 + i;
            const float th = pos * exp2f(-(float)(d & 15) * L2B16);
            const float c = cosf(th), sn = sinf(th);
            const float rot = (d < 16) ? -b2f(yu[i]) : b2f(yu[i]);
            xf[i] = xf[i] * c + rot * sn;
        }
    }
    bf16_t ou[8];
#pragma unroll
    for (int i = 0; i < 8; i++) ou[i] = f2b(xf[i]);
    bf16_t* dst = ((which == 0) ? Qo : Ko) + ((size_t)(b * NH_ + nh) * S_ + s) * HS_ + d0;
    *(bf16x8*)dst = *(const bf16x8*)ou;
}

// ---------------- causal flash attention ----------------
// Block (256 thr, 4 waves) processes TWO 64-row q-tiles: (31-p) then (p),
// so every block does exactly 33 KVBLK=64 steps (uniform work, no tail).
// K LDS [64][128] and V^T LDS [128][64] both XOR-swizzled (byte ^= (row&7)<<4),
// staged via pre-swizzled global source addrs (global_load_lds writes linear).
__global__ __launch_bounds__(256) void attn_fwd(const bf16_t* __restrict__ Q,
                                                const bf16_t* __restrict__ Kv,
                                                const bf16_t* __restrict__ Vt,
                                                const float* __restrict__ amask,
                                                bf16_t* __restrict__ ctx) {
    __shared__ __align__(16) bf16_t Ks[64 * 128];
    __shared__ __align__(16) bf16_t Vs[128 * 64];
    __shared__ __align__(16) bf16_t Ps[4][16 * 72];   // pad 64->72 (bank spread)

    const int id = (int)(blockIdx.x + (blockIdx.y << 4));     // 0..511
    const int wg = ((id & 7) << 6) + (id >> 3);               // XCD-bijective swizzle
    const int pair = wg & 15;
    const int bh = wg >> 4;
    const int b = bh >> 4, h = bh & 15;
    const int tid = threadIdx.x, wid = tid >> 6, lane = tid & 63;
    const int lr = lane & 15, ls = lane >> 4;
    const float* am = amask + (size_t)b * S_;

#pragma unroll 1
    for (int half = 0; half < 2; ++half) {
        const int qt = half ? pair : (31 - pair);
        const int q0 = qt << 6;

        bf16x8 qf[4];
        const bf16_t* qp = Q + ((size_t)bh * S_ + q0 + wid * 16 + lr) * HS_;
#pragma unroll
        for (int dk = 0; dk < 4; dk++) qf[dk] = *(const bf16x8*)(qp + dk * 32 + ls * 8);

        float mrun[4], lrun[4];
        f32x4 oacc[8];
#pragma unroll
        for (int j = 0; j < 4; j++) { mrun[j] = -3.0e38f; lrun[j] = 0.f; }
#pragma unroll
        for (int dt = 0; dt < 8; dt++) oacc[dt] = (f32x4){0.f, 0.f, 0.f, 0.f};

        const int qrb = q0 + wid * 16 + ls * 4;

#pragma unroll 1
        for (int step = 0; step <= qt; ++step) {
            const int kv0 = step << 6;
            __syncthreads();
#pragma unroll
            for (int jj = 0; jj < 4; jj++) {
                const int c = (wid << 2) + jj;
                const int rk = (c << 2) + (lane >> 4);        // K row 0..63
                async16(Ks + c * 512,
                        Kv + ((size_t)bh * S_ + kv0 + rk) * HS_
                           + (((lane & 15) ^ (rk & 7)) << 3));
                const int rv = (c << 3) + (lane >> 3);        // V^T row 0..127
                async16(Vs + c * 512,
                        Vt + ((size_t)bh * HS_ + rv) * S_ + kv0
                           + (((lane & 7) ^ (rv & 7)) << 3));
            }
            __syncthreads();

            f32x4 sacc[4];
#pragma unroll
            for (int t = 0; t < 4; t++) sacc[t] = (f32x4){0.f, 0.f, 0.f, 0.f};
#pragma unroll
            for (int t = 0; t < 4; t++)
#pragma unroll
                for (int dk = 0; dk < 4; dk++) {
                    const int row = t * 16 + lr;
                    bf16x8 kf = *(const bf16x8*)
                        &Ks[row * 128 + (((dk * 4 + ls) ^ (row & 7)) << 3)];
                    sacc[t] = mfma16(qf[dk], kf, sacc[t]);
                }

            const bool diag = (step == qt);
            float sv[4][4], rmax[4];
#pragma unroll
            for (int j = 0; j < 4; j++) {
#pragma unroll
                for (int t = 0; t < 4; t++) {
                    const int kvp = kv0 + t * 16 + lr;
                    float v = sacc[t][j] * NORM_ + am[kvp];
                    if (diag && kvp > qrb + j) v = -3.0e38f;
                    sv[t][j] = v;
                }
                rmax[j] = fmaxf(fmaxf(sv[0][j], sv[1][j]), fmaxf(sv[2][j], sv[3][j]));
            }
#pragma unroll
            for (int off = 1; off < 16; off <<= 1)
#pragma unroll
                for (int j = 0; j < 4; j++)
                    rmax[j] = fmaxf(rmax[j], __shfl_xor(rmax[j], off));

            float scj[4], psum[4];
#pragma unroll
            for (int j = 0; j < 4; j++) {
                const float mnew = fmaxf(mrun[j], rmax[j]);
                scj[j] = __expf(mrun[j] - mnew);
                mrun[j] = mnew;
                psum[j] = 0.f;
#pragma unroll
                for (int t = 0; t < 4; t++) {
                    const float p = __expf(sv[t][j] - mnew);
                    psum[j] += p;
                    Ps[wid][(ls * 4 + j) * 72 + t * 16 + lr] = f2b(p);
                }
            }
#pragma unroll
            for (int off = 1; off < 16; off <<= 1)
#pragma unroll
                for (int j = 0; j < 4; j++) psum[j] += __shfl_xor(psum[j], off);
#pragma unroll
            for (int j = 0; j < 4; j++) {
                lrun[j] = lrun[j] * scj[j] + psum[j];
#pragma unroll
                for (int dt = 0; dt < 8; dt++) oacc[dt][j] *= scj[j];
            }

            bf16x8 pf[2];
#pragma unroll
            for (int hh = 0; hh < 2; hh++)
                pf[hh] = *(const bf16x8*)&Ps[wid][lr * 72 + hh * 32 + ls * 8];
#pragma unroll
            for (int dt = 0; dt < 8; dt++)
#pragma unroll
                for (int hh = 0; hh < 2; hh++) {
                    const int vrow = dt * 16 + lr;
                    bf16x8 vf = *(const bf16x8*)
                        &Vs[vrow * 64 + (((hh * 4 + ls) ^ (vrow & 7)) << 3)];
                    oacc[dt] = mfma16(pf[hh], vf, oacc[dt]);
                }
        }

#pragma unroll
        for (int j = 0; j < 4; j++) {
            const float inv = 1.0f / lrun[j];
            bf16_t* dst = ctx + ((size_t)b * S_ + q0 + wid * 16 + ls * 4 + j) * H_ + h * HS_;
#pragma unroll
            for (int dt = 0; dt < 8; dt++) dst[dt * 16 + lr] = f2b(oacc[dt][j] * inv);
        }
    }
}

extern "C" void kernel_launch(void* const* d_in, const int* in_sizes, int n_in,
                              void* d_out, int out_size, void* d_ws, size_t ws_size,
                              hipStream_t stream) {
    const float* hs   = (const float*)d_in[0];
    const float* am   = (const float*)d_in[1];
    const int*   pos  = (const int*)d_in[2];
    const float* Wqkv = (const float*)d_in[3];
    const float* bqkv = (const float*)d_in[4];
    const float* Wd   = (const float*)d_in[5];
    const float* bd   = (const float*)d_in[6];
    float* out = (float*)d_out;
    char*  ws  = (char*)d_ws;

    const size_t MB = 1024 * 1024;
    bf16_t* X    = (bf16_t*)(ws);              // 16 MB (reused as ctx)
    bf16_t* WqT  = (bf16_t*)(ws + 16 * MB);    // 24 MB
    bf16_t* WdT  = (bf16_t*)(ws + 40 * MB);    // 8 MB
    bf16_t* QKVb = (bf16_t*)(ws + 48 * MB);    // 48 MB
    bf16_t* Qb   = (bf16_t*)(ws + 96 * MB);    // 16 MB
    bf16_t* Kb   = (bf16_t*)(ws + 112 * MB);   // 16 MB
    bf16_t* Vtb  = (bf16_t*)(ws + 128 * MB);   // 16 MB
    bf16_t* ctx  = X;

    cvt_bf16<<<4096, 256, 0, stream>>>(hs, X);
    transpose_cvt<<<dim3(6144 / 32, 2048 / 32), 256, 0, stream>>>(Wqkv, WqT, 2048, 6144);
    transpose_cvt<<<dim3(2048 / 32, 2048 / 32), 256, 0, stream>>>(Wd, WdT, 2048, 2048);
    gemm_bias<1><<<dim3(6144 / 128, 4096 / 128), 256, 0, stream>>>(X, WqT, bqkv, QKVb,
                                                                   4096, 6144, 2048);
    rope_scatter<<<12288, 256, 0, stream>>>(QKVb, pos, Qb, Kb, Vtb);
    attn_fwd<<<dim3(16, 32), 256, 0, stream>>>(Qb, Kb, Vtb, am, ctx);
    gemm_bias<0><<<dim3(2048 / 128, 4096 / 128), 256, 0, stream>>>(ctx, WdT, bd, out,
                                                                   4096, 2048, 2048);
}